// Round 11
// baseline (422.787 us; speedup 1.0000x reference)
//
#include <hip/hip_runtime.h>
#include <stdint.h>

#define D 64
#define PNBLK 512     // blocks for hist/place passes (2 per CU)
#define NBMAX 400     // max buckets (nb = ceil(nn/256) = 391)
#define CAPS 16       // sortedS staging entries per bucket (64B line)
#define CAPD 32       // sortedD staging bytes per bucket (32B flush)
#define XPB 512       // xpass blocks
#define XPST 272      // Xpart row stride (258 rounded up)

__device__ __forceinline__ uint32_t rup8(uint32_t v) { return (v + 7u) & ~7u; }

// ---------------- zero (fallback) ----------------
__global__ void zero_kernel(float* __restrict__ p, int n) {
    int i = blockIdx.x * blockDim.x + threadIdx.x;
    if (i < n) p[i] = 0.0f;
}

// =====================================================================
// Fallback path (global-atomic) — used only if ws too small
// =====================================================================
__global__ void cnt_kernel(const int* __restrict__ dst, float* __restrict__ cnt, int ne) {
    int i = blockIdx.x * blockDim.x + threadIdx.x;
    if (i < ne) atomicAdd(&cnt[dst[i]], 1.0f);
}
__global__ void scatter_kernel(const int* __restrict__ src, const int* __restrict__ dst,
                               const float* __restrict__ r, float* __restrict__ an, int ne) {
    int i = blockIdx.x * blockDim.x + threadIdx.x;
    if (i < ne) atomicAdd(&an[src[i]], r[dst[i]]);
}
__global__ void r0_kernel(const float* __restrict__ cnt, float* __restrict__ r, int nn) {
    int i = blockIdx.x * blockDim.x + threadIdx.x;
    if (i < nn) r[i] = (1.0f / (float)nn) / fmaxf(cnt[i], 1.0f);
}
__global__ void rdiv_kernel(const float* __restrict__ a, const float* __restrict__ cnt,
                            float* __restrict__ r, int nn) {
    int i = blockIdx.x * blockDim.x + threadIdx.x;
    if (i < nn) r[i] = a[i] / fmaxf(cnt[i], 1.0f);
}

// =====================================================================
// Bucketed path
// =====================================================================

// Phase 1: per-block histograms (quad LDS copies to cut bank-conflict serialization).
__global__ __launch_bounds__(512) void hist_kernel(
        const int* __restrict__ src, const int* __restrict__ dst,
        uint32_t* __restrict__ blkhistS, uint32_t* __restrict__ blkhistD,
        int ne, int nb, int chunk) {
    __shared__ uint32_t hS[4][NBMAX], hD[4][NBMAX];
    const int T = blockDim.x, tid = threadIdx.x;
    for (int i = tid; i < nb; i += T) {
        hS[0][i] = 0u; hS[1][i] = 0u; hS[2][i] = 0u; hS[3][i] = 0u;
        hD[0][i] = 0u; hD[1][i] = 0u; hD[2][i] = 0u; hD[3][i] = 0u;
    }
    __syncthreads();
    const int cp = tid & 3;
    int beg = blockIdx.x * chunk;
    int end = min(beg + chunk, ne);
    for (int base = beg; base < end; base += T * 4) {
        int e0 = base + tid * 4;
        if (e0 + 3 < end) {
            int4 s4 = *(const int4*)(src + e0);
            int4 d4 = *(const int4*)(dst + e0);
            atomicAdd(&hS[cp][((uint32_t)s4.x) >> 8], 1u);
            atomicAdd(&hS[cp][((uint32_t)s4.y) >> 8], 1u);
            atomicAdd(&hS[cp][((uint32_t)s4.z) >> 8], 1u);
            atomicAdd(&hS[cp][((uint32_t)s4.w) >> 8], 1u);
            atomicAdd(&hD[cp][((uint32_t)d4.x) >> 8], 1u);
            atomicAdd(&hD[cp][((uint32_t)d4.y) >> 8], 1u);
            atomicAdd(&hD[cp][((uint32_t)d4.z) >> 8], 1u);
            atomicAdd(&hD[cp][((uint32_t)d4.w) >> 8], 1u);
        } else {
            for (int k = 0; k < 4; k++) {
                int e = e0 + k;
                if (e < end) {
                    atomicAdd(&hS[cp][((uint32_t)src[e]) >> 8], 1u);
                    atomicAdd(&hD[cp][((uint32_t)dst[e]) >> 8], 1u);
                }
            }
        }
    }
    __syncthreads();
    for (int i = tid; i < nb; i += T) {
        blkhistS[(size_t)blockIdx.x * nb + i] = hS[0][i] + hS[1][i] + hS[2][i] + hS[3][i];
        blkhistD[(size_t)blockIdx.x * nb + i] = hD[0][i] + hD[1][i] + hD[2][i] + hD[3][i];
    }
}

// Phase 2a: per-(block,bucket) intra-column prefix + column total, one pass.
// offs EXCLUDES the bucket base (place adds bstart[b]). grid = 2*nb, 64 thr.
__global__ __launch_bounds__(64) void reduceoffs_kernel(
        const uint32_t* __restrict__ blkhistS, const uint32_t* __restrict__ blkhistD,
        uint32_t* __restrict__ offsS, uint32_t* __restrict__ offsD,
        uint32_t* __restrict__ totS, uint32_t* __restrict__ totD, int nb) {
    int which = (blockIdx.x >= nb) ? 1 : 0;   // 0=S, 1=D
    int b = blockIdx.x - which * nb;
    const uint32_t* bh = which ? blkhistD : blkhistS;
    uint32_t* of       = which ? offsD    : offsS;
    uint32_t* to       = which ? totD     : totS;
    int lane = threadIdx.x;
    const int K = PNBLK / 64;
    uint32_t v[K];
    uint32_t s = 0;
    int base = lane * K;
    #pragma unroll
    for (int k = 0; k < K; k++) {
        uint32_t c = bh[(size_t)(base + k) * nb + b];
        v[k] = which ? c : rup8(c);
        s += v[k];
    }
    uint32_t inc = s;
    #pragma unroll
    for (int off = 1; off < 64; off <<= 1) {
        uint32_t nbr = __shfl_up(inc, off, 64);
        if (lane >= off) inc += nbr;
    }
    uint32_t run = inc - s;                    // exclusive prefix, no base
    #pragma unroll
    for (int k = 0; k < K; k++) { of[(size_t)(base + k) * nb + b] = run; run += v[k]; }
    if (lane == 63) to[b] = inc;               // column total
}

// Phase 2b: exclusive scan of totals -> bucket starts. grid=2, T=512.
// Also zeros X and the 8 grid-barrier slots for adjoint_kernel.
__global__ __launch_bounds__(512) void scan_kernel(
        const uint32_t* __restrict__ totS, const uint32_t* __restrict__ totD,
        uint32_t* __restrict__ bstartS, uint32_t* __restrict__ bstartD,
        float* __restrict__ X, uint32_t* __restrict__ bar, int nb) {
    const int isS = (blockIdx.x == 0);
    const uint32_t* to = isS ? totS : totD;
    uint32_t* bs       = isS ? bstartS : bstartD;
    const int tid = threadIdx.x;
    if (!isS) {
        if (tid < 4 * D + 2) X[tid] = 0.0f;
        if (tid >= 500 && tid < 508) bar[tid - 500] = 0u;
    }
    uint32_t tot = (tid < nb) ? to[tid] : 0u;
    int lane = tid & 63, wid = tid >> 6;
    uint32_t incl = tot;
    #pragma unroll
    for (int off = 1; off < 64; off <<= 1) {
        uint32_t nbr = __shfl_up(incl, off, 64);
        if (lane >= off) incl += nbr;
    }
    __shared__ uint32_t wsum[8];
    if (lane == 63) wsum[wid] = incl;
    __syncthreads();
    if (wid == 0 && lane < 8) {
        uint32_t w = wsum[lane], wi = w;
        #pragma unroll
        for (int off = 1; off < 8; off <<= 1) {
            uint32_t nbr = __shfl_up(wi, off, 8);
            if (lane >= off) wi += nbr;
        }
        wsum[lane] = wi - w;
    }
    __syncthreads();
    uint32_t excl = incl - tot + wsum[wid];
    if (tid < nb) bs[tid] = excl;
    if (tid == nb - 1) bs[nb] = excl + tot;
}

// Phase 3: place with LDS write-combining (unchanged). Barrier discipline for
// `again`: register read + extra barrier (R4 hang lesson).
__global__ __launch_bounds__(512) void place_kernel(
        const int* __restrict__ src, const int* __restrict__ dst,
        const uint32_t* __restrict__ offsS, const uint32_t* __restrict__ offsD,
        const uint32_t* __restrict__ bstartS, const uint32_t* __restrict__ bstartD,
        uint32_t* __restrict__ sortedS, uint8_t* __restrict__ sortedD,
        int ne, int nb, int chunk, uint32_t sentinel) {
    __shared__ uint32_t stS[NBMAX * CAPS];
    __shared__ uint8_t  stD[NBMAX * CAPD];
    __shared__ uint32_t pendS[NBMAX], pendD[NBMAX];
    __shared__ uint32_t gposS[NBMAX], gposD[NBMAX];
    __shared__ int again;
    const int T = blockDim.x, tid = threadIdx.x;
    for (int i = tid; i < nb; i += T) {
        pendS[i] = 0u; pendD[i] = 0u;
        gposS[i] = bstartS[i] + offsS[(size_t)blockIdx.x * nb + i];
        gposD[i] = bstartD[i] + offsD[(size_t)blockIdx.x * nb + i];
    }
    __syncthreads();
    int beg = blockIdx.x * chunk;
    int end = min(beg + chunk, ne);
    for (int base = beg; base < end; base += T * 4) {
        uint32_t vS[4]; uint8_t vD[4]; int bS[4], bD[4]; bool hS[4], hD[4];
        int e0 = base + tid * 4;
        if (e0 + 3 < end) {
            int4 s4 = *(const int4*)(src + e0);
            int4 d4 = *(const int4*)(dst + e0);
            int sv[4] = {s4.x, s4.y, s4.z, s4.w};
            int dv[4] = {d4.x, d4.y, d4.z, d4.w};
            #pragma unroll
            for (int k = 0; k < 4; k++) {
                uint32_t s = (uint32_t)sv[k], d = (uint32_t)dv[k];
                bS[k] = s >> 8; vS[k] = ((s & 255u) << 17) | d;
                bD[k] = d >> 8; vD[k] = (uint8_t)(d & 255u);
                hS[k] = true; hD[k] = true;
            }
        } else {
            #pragma unroll
            for (int k = 0; k < 4; k++) {
                int e = e0 + k;
                bool ok = e < end;
                hS[k] = ok; hD[k] = ok;
                if (ok) {
                    uint32_t s = (uint32_t)src[e], d = (uint32_t)dst[e];
                    bS[k] = s >> 8; vS[k] = ((s & 255u) << 17) | d;
                    bD[k] = d >> 8; vD[k] = (uint8_t)(d & 255u);
                } else { bS[k] = 0; bD[k] = 0; vS[k] = 0; vD[k] = 0; }
            }
        }
        while (true) {
            if (tid == 0) again = 0;
            __syncthreads();
            #pragma unroll
            for (int k = 0; k < 4; k++) {
                if (hS[k]) {
                    uint32_t p = atomicAdd(&pendS[bS[k]], 1u);
                    if (p < CAPS) { stS[bS[k] * CAPS + p] = vS[k]; hS[k] = false; }
                }
                if (hD[k]) {
                    uint32_t p = atomicAdd(&pendD[bD[k]], 1u);
                    if (p < CAPD) { stD[bD[k] * CAPD + p] = vD[k]; hD[k] = false; }
                }
            }
            if (hS[0] | hS[1] | hS[2] | hS[3] | hD[0] | hD[1] | hD[2] | hD[3]) again = 1;
            __syncthreads();
            for (int bb = tid; bb < nb; bb += T) {
                uint32_t n = min(pendS[bb], (uint32_t)CAPS);
                if (n == CAPS) {
                    uint32_t g = gposS[bb];            // multiple of 8 -> 32B aligned
                    uint4* dstp = (uint4*)(sortedS + g);
                    const uint4* srcp = (const uint4*)(stS + bb * CAPS);
                    dstp[0] = srcp[0]; dstp[1] = srcp[1];
                    dstp[2] = srcp[2]; dstp[3] = srcp[3];
                    gposS[bb] = g + CAPS;
                    pendS[bb] = 0u;
                } else pendS[bb] = n;
                n = min(pendD[bb], (uint32_t)CAPD);
                if (n == CAPD) {
                    uint32_t g = gposD[bb];
                    #pragma unroll
                    for (int k = 0; k < CAPD; k++) sortedD[g + k] = stD[bb * CAPD + k];
                    gposD[bb] = g + CAPD;
                    pendD[bb] = 0u;
                } else pendD[bb] = n;
            }
            __syncthreads();
            const int cont = again;     // read flag into register...
            __syncthreads();            // ...and fence before tid0 resets it
            if (!cont) break;
        }
    }
    // final flush: S padded to rup8(n) with sentinels (region exact), D exact.
    for (int bb = tid; bb < nb; bb += T) {
        uint32_t n = pendS[bb];
        if (n > 0) {
            uint32_t g = gposS[bb];
            uint32_t m = rup8(n);
            uint32_t tmp[CAPS];
            for (uint32_t k = 0; k < m; k++) tmp[k] = (k < n) ? stS[bb * CAPS + k] : sentinel;
            for (uint32_t k = 0; k < m; k += 8) {
                uint4* dstp = (uint4*)(sortedS + g + k);
                dstp[0] = *(const uint4*)(tmp + k);
                dstp[1] = *(const uint4*)(tmp + k + 4);
            }
        }
        uint32_t nD = pendD[bb], gD = gposD[bb];
        for (uint32_t k = 0; k < nD; k++) sortedD[gD + k] = stD[bb * CAPD + k];
    }
}

// Arrival/release grid barrier. bar[0]=arrival counter, bar[1]=release flag
// (fresh pair per barrier, zeroed by scan_kernel each launch). Pollers use
// agent-scope atomic LOADS (no RMW serialization — the R10 lesson: polling
// with atomicAdd(bar,0) queues RMWs and delays the stragglers' arrivals).
__device__ __forceinline__ void grid_barrier(uint32_t* bar, uint32_t nblocks) {
    __syncthreads();
    if (threadIdx.x == 0) {
        __threadfence();                                  // release my writes
        uint32_t t = __hip_atomic_fetch_add(bar, 1u, __ATOMIC_ACQ_REL,
                                            __HIP_MEMORY_SCOPE_AGENT);
        if (t == nblocks - 1u) {
            __hip_atomic_store(bar + 1, 1u, __ATOMIC_RELEASE,
                               __HIP_MEMORY_SCOPE_AGENT);
        } else {
            while (__hip_atomic_load(bar + 1, __ATOMIC_ACQUIRE,
                                     __HIP_MEMORY_SCOPE_AGENT) == 0u) {
                __builtin_amdgcn_s_sleep(16);
            }
        }
        __threadfence();                                  // acquire others'
    }
    __syncthreads();
}

// Fused adjoint chain: cnt -> a1 -> a2 -> a3 with 3 grid barriers.
// grid = nb blocks, all co-resident (8 waves/block, min 4 waves/EU => >=2
// blocks/CU => capacity >= 512 > nb). cnt lives in a register across phases.
__global__ __launch_bounds__(512, 4) void adjoint_kernel(
        const uint32_t* __restrict__ sortedS, const uint32_t* __restrict__ bstartS,
        const uint8_t* __restrict__ sortedD, const uint32_t* __restrict__ bstartD,
        float* __restrict__ rA, float* __restrict__ rB,
        float* __restrict__ a1, float* __restrict__ a2, float* __restrict__ a3,
        uint32_t* __restrict__ bar, int nn, float invN, int nblocks) {
    const int b = blockIdx.x, tid = threadIdx.x;
    __shared__ uint32_t lds[4 * 256];
    float* ldsf = (float*)lds;
    const int cp = tid & 3;
    const int v = b * 256 + tid;

    // ---- phase 0: in-degree from sortedD, write rA ----
    lds[tid] = 0u; lds[512 + tid] = 0u;
    __syncthreads();
    {
        uint32_t beg = bstartD[b], end = bstartD[b + 1];
        for (uint32_t e = beg + tid; e < end; e += 512)
            atomicAdd(&lds[cp * 256 + sortedD[e]], 1u);
    }
    __syncthreads();
    float myCnt = 1.0f;
    if (tid < 256) {
        float cf = (float)(lds[tid] + lds[256 + tid] + lds[512 + tid] + lds[768 + tid]);
        myCnt = fmaxf(cf, 1.0f);
        if (v < nn) rA[v] = invN / myCnt;
    }
    if (b == 0 && tid == 0) { rA[nn] = 0.0f; rB[nn] = 0.0f; }
    grid_barrier(bar + 0, (uint32_t)nblocks);

    const uint32_t sbeg = bstartS[b], send = bstartS[b + 1];   // multiples of 8
    // ---- phases 1..3: a_k[v] = sum r_in[dst], r_out = a/cnt ----
    #define SCAT_PHASE(RIN, AOUT, ROUT)                                          \
    {                                                                            \
        lds[tid] = 0u; lds[512 + tid] = 0u;                                      \
        __syncthreads();                                                         \
        for (uint32_t e = sbeg + tid * 4; e < send; e += 512 * 4) {              \
            uint4 p = *(const uint4*)(sortedS + e);                              \
            atomicAdd(&ldsf[cp * 256 + (p.x >> 17)], RIN[p.x & 0x1FFFFu]);       \
            atomicAdd(&ldsf[cp * 256 + (p.y >> 17)], RIN[p.y & 0x1FFFFu]);       \
            atomicAdd(&ldsf[cp * 256 + (p.z >> 17)], RIN[p.z & 0x1FFFFu]);       \
            atomicAdd(&ldsf[cp * 256 + (p.w >> 17)], RIN[p.w & 0x1FFFFu]);       \
        }                                                                        \
        __syncthreads();                                                         \
        if (tid < 256 && v < nn) {                                               \
            float a = ldsf[tid] + ldsf[256 + tid] + ldsf[512 + tid] + ldsf[768 + tid]; \
            AOUT[v] = a;                                                         \
            if (ROUT) ((float*)ROUT)[v] = a / myCnt;                             \
        }                                                                        \
    }
    SCAT_PHASE(rA, a1, rB)
    grid_barrier(bar + 2, (uint32_t)nblocks);
    SCAT_PHASE(rB, a2, rA)
    grid_barrier(bar + 4, (uint32_t)nblocks);
    SCAT_PHASE(rA, a3, ((float*)nullptr))
    #undef SCAT_PHASE
}

// Weighted column-sums of x: float4 loads, LDS tree-reduce, per-block partials.
__global__ __launch_bounds__(256) void xpass_kernel(
        const float* __restrict__ x,
        const float* __restrict__ a1, const float* __restrict__ a2,
        const float* __restrict__ a3, float* __restrict__ Xpart, int nn) {
    const int tid = threadIdx.x;
    const int cg = tid & 15;    // column group (4 cols)
    const int rs = tid >> 4;    // row slot 0..15
    float4 c0 = {0,0,0,0}, c1 = {0,0,0,0}, c2 = {0,0,0,0}, c3 = {0,0,0,0};
    float ss1 = 0.f, ss2 = 0.f;
    for (int i = blockIdx.x * 16 + rs; i < nn; i += gridDim.x * 16) {
        float4 xv = *(const float4*)(x + (size_t)i * D + cg * 4);
        float w1 = a1[i], w2 = a2[i], w3 = a3[i];
        c0.x += xv.x; c0.y += xv.y; c0.z += xv.z; c0.w += xv.w;
        c1.x = fmaf(w1, xv.x, c1.x); c1.y = fmaf(w1, xv.y, c1.y);
        c1.z = fmaf(w1, xv.z, c1.z); c1.w = fmaf(w1, xv.w, c1.w);
        c2.x = fmaf(w2, xv.x, c2.x); c2.y = fmaf(w2, xv.y, c2.y);
        c2.z = fmaf(w2, xv.z, c2.z); c2.w = fmaf(w2, xv.w, c2.w);
        c3.x = fmaf(w3, xv.x, c3.x); c3.y = fmaf(w3, xv.y, c3.y);
        c3.z = fmaf(w3, xv.z, c3.z); c3.w = fmaf(w3, xv.w, c3.w);
        if (cg == 0) { ss1 += w1; ss2 += w2; }
    }
    __shared__ float4 sm[4][16][16];   // [set][rs][cg]
    __shared__ float sms1[16], sms2[16];
    sm[0][rs][cg] = c0; sm[1][rs][cg] = c1; sm[2][rs][cg] = c2; sm[3][rs][cg] = c3;
    if (cg == 0) { sms1[rs] = ss1; sms2[rs] = ss2; }
    __syncthreads();
    for (int s = 8; s; s >>= 1) {
        if (rs < s) {
            #pragma unroll
            for (int k = 0; k < 4; k++) {
                float4 a = sm[k][rs][cg], b = sm[k][rs + s][cg];
                a.x += b.x; a.y += b.y; a.z += b.z; a.w += b.w;
                sm[k][rs][cg] = a;
            }
            if (cg == 0) { sms1[rs] += sms1[rs + s]; sms2[rs] += sms2[rs + s]; }
        }
        __syncthreads();
    }
    float* outp = Xpart + (size_t)blockIdx.x * XPST;
    {
        int k = tid >> 6, col = tid & 63;
        outp[tid] = ((const float*)&sm[k][0][col >> 2])[col & 3];
    }
    if (tid == 0) outp[256] = sms1[0];
    if (tid == 1) outp[257] = sms2[0];
}

// Reduce Xpart over blocks -> X. grid = 258 blocks, 64 threads.
__global__ __launch_bounds__(64) void xreduce_kernel(
        const float* __restrict__ Xpart, float* __restrict__ X, int nxb) {
    int j = blockIdx.x;           // 0..257
    int lane = threadIdx.x;
    float s = 0.f;
    for (int b = lane; b < nxb; b += 64) s += Xpart[(size_t)b * XPST + j];
    #pragma unroll
    for (int off = 32; off; off >>= 1) s += __shfl_down(s, off);
    if (lane == 0) X[j] = s;
}

// Chain of 64x64 matvecs; 256 threads.
__global__ __launch_bounds__(256) void final_kernel(const float* __restrict__ X,
    const float* __restrict__ Wl1, const float* __restrict__ bl1, const float* __restrict__ Wr1,
    const float* __restrict__ Wl2, const float* __restrict__ bl2, const float* __restrict__ Wr2,
    const float* __restrict__ Wl3, const float* __restrict__ bl3, const float* __restrict__ Wr3,
    const float* __restrict__ Wlin, const float* __restrict__ blin,
    float* __restrict__ out, int nn) {
    const int tid = threadIdx.x;
    const int t = tid >> 2, q = tid & 3, c0 = q * 16;
    __shared__ float X1[D], X2[D], X3[D], X4[D];
    __shared__ float m1u[D], m1a1[D], m1a2[D], m2u[D], m2a1[D];
    __shared__ float sred[4];
    if (tid < 64)       X1[tid]       = X[tid] * (1.0f / (float)nn);
    else if (tid < 128) X2[tid - 64]  = X[tid];
    else if (tid < 192) X3[tid - 128] = X[tid];
    else                X4[tid - 192] = X[tid];
    const float s1 = X[4 * D], s2 = X[4 * D + 1];
    __syncthreads();

    float dl2 = 0.f, dl3 = 0.f, dl4 = 0.f, dr1 = 0.f, dr2 = 0.f, dr3 = 0.f;
    #pragma unroll
    for (int k = 0; k < 16; k++) {
        int c = c0 + k;
        float wl = Wl1[t * D + c], wr = Wr1[t * D + c];
        dl2 = fmaf(wl, X2[c], dl2); dl3 = fmaf(wl, X3[c], dl3); dl4 = fmaf(wl, X4[c], dl4);
        dr1 = fmaf(wr, X1[c], dr1); dr2 = fmaf(wr, X2[c], dr2); dr3 = fmaf(wr, X3[c], dr3);
    }
    #define RED4(v) { v += __shfl_down(v, 2, 4); v += __shfl_down(v, 1, 4); }
    RED4(dl2) RED4(dl3) RED4(dl4) RED4(dr1) RED4(dr2) RED4(dr3)
    if (q == 0) {
        m1u[t]  = dl2 + bl1[t]      + dr1;
        m1a1[t] = dl3 + bl1[t] * s1 + dr2;
        m1a2[t] = dl4 + bl1[t] * s2 + dr3;
    }
    __syncthreads();

    float el1 = 0.f, el2 = 0.f, er0 = 0.f, er1 = 0.f;
    #pragma unroll
    for (int k = 0; k < 16; k++) {
        int c = c0 + k;
        float wl = Wl2[t * D + c], wr = Wr2[t * D + c];
        el1 = fmaf(wl, m1a1[c], el1); el2 = fmaf(wl, m1a2[c], el2);
        er0 = fmaf(wr, m1u[c],  er0); er1 = fmaf(wr, m1a1[c], er1);
    }
    RED4(el1) RED4(el2) RED4(er0) RED4(er1)
    if (q == 0) {
        m2u[t]  = el1 + bl2[t]      + er0;
        m2a1[t] = el2 + bl2[t] * s1 + er1;
    }
    __syncthreads();

    float fl = 0.f, fr = 0.f;
    #pragma unroll
    for (int k = 0; k < 16; k++) {
        int c = c0 + k;
        fl = fmaf(Wl3[t * D + c], m2a1[c], fl);
        fr = fmaf(Wr3[t * D + c], m2u[c],  fr);
    }
    RED4(fl) RED4(fr)
    float contrib = 0.f;
    if (q == 0) contrib = Wlin[t] * (fl + bl3[t] + fr);
    #pragma unroll
    for (int off = 32; off; off >>= 1) contrib += __shfl_down(contrib, off);
    if ((tid & 63) == 0) sred[tid >> 6] = contrib;
    __syncthreads();
    if (tid == 0) out[0] = sred[0] + sred[1] + sred[2] + sred[3] + blin[0];
}

extern "C" void kernel_launch(void* const* d_in, const int* in_sizes, int n_in,
                              void* d_out, int out_size, void* d_ws, size_t ws_size,
                              hipStream_t stream) {
    const float* x    = (const float*)d_in[0];
    const int*   ei   = (const int*)d_in[1];
    const float* Wl1  = (const float*)d_in[2];
    const float* bl1  = (const float*)d_in[3];
    const float* Wr1  = (const float*)d_in[4];
    const float* Wl2  = (const float*)d_in[5];
    const float* bl2  = (const float*)d_in[6];
    const float* Wr2  = (const float*)d_in[7];
    const float* Wl3  = (const float*)d_in[8];
    const float* bl3  = (const float*)d_in[9];
    const float* Wr3  = (const float*)d_in[10];
    const float* Wlin = (const float*)d_in[11];
    const float* blin = (const float*)d_in[12];
    float* out = (float*)d_out;

    const int nn = in_sizes[0] / D;        // 100000
    const int ne = in_sizes[1] / 2;        // 3200000
    const int* srcIdx = ei;
    const int* dstIdx = ei + ne;
    const int nb = (nn + 255) >> 8;        // 391

    char* base = (char*)d_ws;
    size_t cur = 0;
    auto alloc = [&](size_t bytes) -> void* {
        void* p = base + cur;
        cur = (cur + bytes + 255) & ~(size_t)255;
        return p;
    };
    float*    cnt      = (float*)alloc((size_t)nn * 4);            // fallback only
    float*    a1       = (float*)alloc((size_t)nn * 4);
    float*    a2       = (float*)alloc((size_t)nn * 4);
    float*    a3       = (float*)alloc((size_t)nn * 4);
    float*    rA       = (float*)alloc((size_t)(nn + 1) * 4);      // +1 sentinel
    float*    rB       = (float*)alloc((size_t)(nn + 1) * 4);
    float*    X        = (float*)alloc((4 * D + 2) * 4);
    float*    Xpart    = (float*)alloc((size_t)XPB * XPST * 4);
    size_t    zend     = cur;
    uint32_t* bar      = (uint32_t*)alloc(8 * 4);
    uint32_t* blkhistS = (uint32_t*)alloc((size_t)PNBLK * nb * 4);
    uint32_t* blkhistD = (uint32_t*)alloc((size_t)PNBLK * nb * 4);
    uint32_t* offsS    = (uint32_t*)alloc((size_t)PNBLK * nb * 4);
    uint32_t* offsD    = (uint32_t*)alloc((size_t)PNBLK * nb * 4);
    uint32_t* bstartS  = (uint32_t*)alloc((size_t)(nb + 1) * 4);
    uint32_t* bstartD  = (uint32_t*)alloc((size_t)(nb + 1) * 4);
    uint32_t* totS     = (uint32_t*)alloc((size_t)nb * 4);
    uint32_t* totD     = (uint32_t*)alloc((size_t)nb * 4);
    uint32_t* sortedS  = (uint32_t*)alloc(((size_t)ne + (size_t)PNBLK * nb * 7) * 4); // padded
    uint8_t*  sortedD  = (uint8_t*)alloc((size_t)ne);
    const size_t need = cur;

    const int B = 256;
    if (need <= ws_size && nn <= 131071 && nb <= NBMAX && nb <= 512) {
        const int chunk = ((ne + PNBLK - 1) / PNBLK + 3) & ~3;
        hipLaunchKernelGGL(hist_kernel, dim3(PNBLK), dim3(512), 0, stream,
                           srcIdx, dstIdx, blkhistS, blkhistD, ne, nb, chunk);
        hipLaunchKernelGGL(reduceoffs_kernel, dim3(2 * nb), dim3(64), 0, stream,
                           blkhistS, blkhistD, offsS, offsD, totS, totD, nb);
        hipLaunchKernelGGL(scan_kernel, dim3(2), dim3(512), 0, stream,
                           totS, totD, bstartS, bstartD, X, bar, nb);
        hipLaunchKernelGGL(place_kernel, dim3(PNBLK), dim3(512), 0, stream,
                           srcIdx, dstIdx, offsS, offsD, bstartS, bstartD,
                           sortedS, sortedD, ne, nb, chunk, (uint32_t)nn);
        hipLaunchKernelGGL(adjoint_kernel, dim3(nb), dim3(512), 0, stream,
                           sortedS, bstartS, sortedD, bstartD, rA, rB, a1, a2, a3,
                           bar, nn, 1.0f / (float)nn, nb);
    } else {
        const int zn = (int)(zend / 4);
        hipLaunchKernelGGL(zero_kernel, dim3((zn + B - 1) / B), dim3(B), 0, stream, (float*)d_ws, zn);
        hipLaunchKernelGGL(cnt_kernel,  dim3((ne + B - 1) / B), dim3(B), 0, stream, dstIdx, cnt, ne);
        hipLaunchKernelGGL(r0_kernel,   dim3((nn + B - 1) / B), dim3(B), 0, stream, cnt, rA, nn);
        hipLaunchKernelGGL(scatter_kernel, dim3((ne + B - 1) / B), dim3(B), 0, stream, srcIdx, dstIdx, rA, a1, ne);
        hipLaunchKernelGGL(rdiv_kernel, dim3((nn + B - 1) / B), dim3(B), 0, stream, a1, cnt, rA, nn);
        hipLaunchKernelGGL(scatter_kernel, dim3((ne + B - 1) / B), dim3(B), 0, stream, srcIdx, dstIdx, rA, a2, ne);
        hipLaunchKernelGGL(rdiv_kernel, dim3((nn + B - 1) / B), dim3(B), 0, stream, a2, cnt, rA, nn);
        hipLaunchKernelGGL(scatter_kernel, dim3((ne + B - 1) / B), dim3(B), 0, stream, srcIdx, dstIdx, rA, a3, ne);
    }

    hipLaunchKernelGGL(xpass_kernel, dim3(XPB), dim3(B), 0, stream, x, a1, a2, a3, Xpart, nn);
    hipLaunchKernelGGL(xreduce_kernel, dim3(4 * D + 2), dim3(64), 0, stream, Xpart, X, XPB);
    hipLaunchKernelGGL(final_kernel, dim3(1), dim3(B), 0, stream, X,
                       Wl1, bl1, Wr1, Wl2, bl2, Wr2, Wl3, bl3, Wr3, Wlin, blin, out, nn);
}

// Round 12
// 153.284 us; speedup vs baseline: 2.7582x; 2.7582x over previous
//
#include <hip/hip_runtime.h>
#include <stdint.h>

#define D 64
#define PNBLK 512     // blocks for hist/place passes (2 per CU)
#define NBMAX 400     // max buckets (nb = ceil(nn/256) = 391)
#define CAPS 16       // sortedS staging entries per bucket (64B line)
#define CAPD 32       // sortedD staging bytes per bucket (32B flush)
#define XPB 512       // xpass blocks (fallback path)
#define XPST 272      // Xpart row stride (258 rounded up)

__device__ __forceinline__ uint32_t rup8(uint32_t v) { return (v + 7u) & ~7u; }

// ---------------- zero (fallback) ----------------
__global__ void zero_kernel(float* __restrict__ p, int n) {
    int i = blockIdx.x * blockDim.x + threadIdx.x;
    if (i < n) p[i] = 0.0f;
}

// =====================================================================
// Fallback path (global-atomic) — used only if ws too small
// =====================================================================
__global__ void cnt_kernel(const int* __restrict__ dst, float* __restrict__ cnt, int ne) {
    int i = blockIdx.x * blockDim.x + threadIdx.x;
    if (i < ne) atomicAdd(&cnt[dst[i]], 1.0f);
}
__global__ void scatter_kernel(const int* __restrict__ src, const int* __restrict__ dst,
                               const float* __restrict__ r, float* __restrict__ an, int ne) {
    int i = blockIdx.x * blockDim.x + threadIdx.x;
    if (i < ne) atomicAdd(&an[src[i]], r[dst[i]]);
}
__global__ void r0_kernel(const float* __restrict__ cnt, float* __restrict__ r, int nn) {
    int i = blockIdx.x * blockDim.x + threadIdx.x;
    if (i < nn) r[i] = (1.0f / (float)nn) / fmaxf(cnt[i], 1.0f);
}
__global__ void rdiv_kernel(const float* __restrict__ a, const float* __restrict__ cnt,
                            float* __restrict__ r, int nn) {
    int i = blockIdx.x * blockDim.x + threadIdx.x;
    if (i < nn) r[i] = a[i] / fmaxf(cnt[i], 1.0f);
}

// Weighted column-sums of x (fallback path): float4 loads, LDS tree-reduce.
__global__ __launch_bounds__(256) void xpass_kernel(
        const float* __restrict__ x,
        const float* __restrict__ a1, const float* __restrict__ a2,
        const float* __restrict__ a3, float* __restrict__ Xpart, int nn) {
    const int tid = threadIdx.x;
    const int cg = tid & 15;
    const int rs = tid >> 4;
    float4 c0 = {0,0,0,0}, c1 = {0,0,0,0}, c2 = {0,0,0,0}, c3 = {0,0,0,0};
    float ss1 = 0.f, ss2 = 0.f;
    for (int i = blockIdx.x * 16 + rs; i < nn; i += gridDim.x * 16) {
        float4 xv = *(const float4*)(x + (size_t)i * D + cg * 4);
        float w1 = a1[i], w2 = a2[i], w3 = a3[i];
        c0.x += xv.x; c0.y += xv.y; c0.z += xv.z; c0.w += xv.w;
        c1.x = fmaf(w1, xv.x, c1.x); c1.y = fmaf(w1, xv.y, c1.y);
        c1.z = fmaf(w1, xv.z, c1.z); c1.w = fmaf(w1, xv.w, c1.w);
        c2.x = fmaf(w2, xv.x, c2.x); c2.y = fmaf(w2, xv.y, c2.y);
        c2.z = fmaf(w2, xv.z, c2.z); c2.w = fmaf(w2, xv.w, c2.w);
        c3.x = fmaf(w3, xv.x, c3.x); c3.y = fmaf(w3, xv.y, c3.y);
        c3.z = fmaf(w3, xv.z, c3.z); c3.w = fmaf(w3, xv.w, c3.w);
        if (cg == 0) { ss1 += w1; ss2 += w2; }
    }
    __shared__ float4 sm[4][16][16];
    __shared__ float sms1[16], sms2[16];
    sm[0][rs][cg] = c0; sm[1][rs][cg] = c1; sm[2][rs][cg] = c2; sm[3][rs][cg] = c3;
    if (cg == 0) { sms1[rs] = ss1; sms2[rs] = ss2; }
    __syncthreads();
    for (int s = 8; s; s >>= 1) {
        if (rs < s) {
            #pragma unroll
            for (int k = 0; k < 4; k++) {
                float4 a = sm[k][rs][cg], b = sm[k][rs + s][cg];
                a.x += b.x; a.y += b.y; a.z += b.z; a.w += b.w;
                sm[k][rs][cg] = a;
            }
            if (cg == 0) { sms1[rs] += sms1[rs + s]; sms2[rs] += sms2[rs + s]; }
        }
        __syncthreads();
    }
    float* outp = Xpart + (size_t)blockIdx.x * XPST;
    {
        int k = tid >> 6, col = tid & 63;
        outp[tid] = ((const float*)&sm[k][0][col >> 2])[col & 3];
    }
    if (tid == 0) outp[256] = sms1[0];
    if (tid == 1) outp[257] = sms2[0];
}

// =====================================================================
// Bucketed path
// =====================================================================

// Phase 1: per-block histograms (quad LDS copies to cut bank-conflict serialization).
__global__ __launch_bounds__(512) void hist_kernel(
        const int* __restrict__ src, const int* __restrict__ dst,
        uint32_t* __restrict__ blkhistS, uint32_t* __restrict__ blkhistD,
        int ne, int nb, int chunk) {
    __shared__ uint32_t hS[4][NBMAX], hD[4][NBMAX];
    const int T = blockDim.x, tid = threadIdx.x;
    for (int i = tid; i < nb; i += T) {
        hS[0][i] = 0u; hS[1][i] = 0u; hS[2][i] = 0u; hS[3][i] = 0u;
        hD[0][i] = 0u; hD[1][i] = 0u; hD[2][i] = 0u; hD[3][i] = 0u;
    }
    __syncthreads();
    const int cp = tid & 3;
    int beg = blockIdx.x * chunk;
    int end = min(beg + chunk, ne);
    for (int base = beg; base < end; base += T * 4) {
        int e0 = base + tid * 4;
        if (e0 + 3 < end) {
            int4 s4 = *(const int4*)(src + e0);
            int4 d4 = *(const int4*)(dst + e0);
            atomicAdd(&hS[cp][((uint32_t)s4.x) >> 8], 1u);
            atomicAdd(&hS[cp][((uint32_t)s4.y) >> 8], 1u);
            atomicAdd(&hS[cp][((uint32_t)s4.z) >> 8], 1u);
            atomicAdd(&hS[cp][((uint32_t)s4.w) >> 8], 1u);
            atomicAdd(&hD[cp][((uint32_t)d4.x) >> 8], 1u);
            atomicAdd(&hD[cp][((uint32_t)d4.y) >> 8], 1u);
            atomicAdd(&hD[cp][((uint32_t)d4.z) >> 8], 1u);
            atomicAdd(&hD[cp][((uint32_t)d4.w) >> 8], 1u);
        } else {
            for (int k = 0; k < 4; k++) {
                int e = e0 + k;
                if (e < end) {
                    atomicAdd(&hS[cp][((uint32_t)src[e]) >> 8], 1u);
                    atomicAdd(&hD[cp][((uint32_t)dst[e]) >> 8], 1u);
                }
            }
        }
    }
    __syncthreads();
    for (int i = tid; i < nb; i += T) {
        blkhistS[(size_t)blockIdx.x * nb + i] = hS[0][i] + hS[1][i] + hS[2][i] + hS[3][i];
        blkhistD[(size_t)blockIdx.x * nb + i] = hD[0][i] + hD[1][i] + hD[2][i] + hD[3][i];
    }
}

// Phase 2a: per-(block,bucket) intra-column prefix + column total, one pass.
// offs EXCLUDES the bucket base (place adds bstart[b]). grid = 2*nb, 64 thr.
__global__ __launch_bounds__(64) void reduceoffs_kernel(
        const uint32_t* __restrict__ blkhistS, const uint32_t* __restrict__ blkhistD,
        uint32_t* __restrict__ offsS, uint32_t* __restrict__ offsD,
        uint32_t* __restrict__ totS, uint32_t* __restrict__ totD, int nb) {
    int which = (blockIdx.x >= nb) ? 1 : 0;   // 0=S, 1=D
    int b = blockIdx.x - which * nb;
    const uint32_t* bh = which ? blkhistD : blkhistS;
    uint32_t* of       = which ? offsD    : offsS;
    uint32_t* to       = which ? totD     : totS;
    int lane = threadIdx.x;
    const int K = PNBLK / 64;
    uint32_t v[K];
    uint32_t s = 0;
    int base = lane * K;
    #pragma unroll
    for (int k = 0; k < K; k++) {
        uint32_t c = bh[(size_t)(base + k) * nb + b];
        v[k] = which ? c : rup8(c);
        s += v[k];
    }
    uint32_t inc = s;
    #pragma unroll
    for (int off = 1; off < 64; off <<= 1) {
        uint32_t nbr = __shfl_up(inc, off, 64);
        if (lane >= off) inc += nbr;
    }
    uint32_t run = inc - s;                    // exclusive prefix, no base
    #pragma unroll
    for (int k = 0; k < K; k++) { of[(size_t)(base + k) * nb + b] = run; run += v[k]; }
    if (lane == 63) to[b] = inc;               // column total
}

// Phase 2b: exclusive scan of totals -> bucket starts. grid=2, T=512.
__global__ __launch_bounds__(512) void scan_kernel(
        const uint32_t* __restrict__ totS, const uint32_t* __restrict__ totD,
        uint32_t* __restrict__ bstartS, uint32_t* __restrict__ bstartD, int nb) {
    const int isS = (blockIdx.x == 0);
    const uint32_t* to = isS ? totS : totD;
    uint32_t* bs       = isS ? bstartS : bstartD;
    const int tid = threadIdx.x;
    uint32_t tot = (tid < nb) ? to[tid] : 0u;
    int lane = tid & 63, wid = tid >> 6;
    uint32_t incl = tot;
    #pragma unroll
    for (int off = 1; off < 64; off <<= 1) {
        uint32_t nbr = __shfl_up(incl, off, 64);
        if (lane >= off) incl += nbr;
    }
    __shared__ uint32_t wsum[8];
    if (lane == 63) wsum[wid] = incl;
    __syncthreads();
    if (wid == 0 && lane < 8) {
        uint32_t w = wsum[lane], wi = w;
        #pragma unroll
        for (int off = 1; off < 8; off <<= 1) {
            uint32_t nbr = __shfl_up(wi, off, 8);
            if (lane >= off) wi += nbr;
        }
        wsum[lane] = wi - w;
    }
    __syncthreads();
    uint32_t excl = incl - tot + wsum[wid];
    if (tid < nb) bs[tid] = excl;
    if (tid == nb - 1) bs[nb] = excl + tot;
}

// Phase 3: place with LDS write-combining, 64B staged lines for S flushed as
// aligned 32B stores, sentinel padding (payload=nn -> r[nn]=0). Barrier
// discipline for `again`: register read + extra barrier (R4 hang lesson).
__global__ __launch_bounds__(512) void place_kernel(
        const int* __restrict__ src, const int* __restrict__ dst,
        const uint32_t* __restrict__ offsS, const uint32_t* __restrict__ offsD,
        const uint32_t* __restrict__ bstartS, const uint32_t* __restrict__ bstartD,
        uint32_t* __restrict__ sortedS, uint8_t* __restrict__ sortedD,
        int ne, int nb, int chunk, uint32_t sentinel) {
    __shared__ uint32_t stS[NBMAX * CAPS];
    __shared__ uint8_t  stD[NBMAX * CAPD];
    __shared__ uint32_t pendS[NBMAX], pendD[NBMAX];
    __shared__ uint32_t gposS[NBMAX], gposD[NBMAX];
    __shared__ int again;
    const int T = blockDim.x, tid = threadIdx.x;
    for (int i = tid; i < nb; i += T) {
        pendS[i] = 0u; pendD[i] = 0u;
        gposS[i] = bstartS[i] + offsS[(size_t)blockIdx.x * nb + i];
        gposD[i] = bstartD[i] + offsD[(size_t)blockIdx.x * nb + i];
    }
    __syncthreads();
    int beg = blockIdx.x * chunk;
    int end = min(beg + chunk, ne);
    for (int base = beg; base < end; base += T * 4) {
        uint32_t vS[4]; uint8_t vD[4]; int bS[4], bD[4]; bool hS[4], hD[4];
        int e0 = base + tid * 4;
        if (e0 + 3 < end) {
            int4 s4 = *(const int4*)(src + e0);
            int4 d4 = *(const int4*)(dst + e0);
            int sv[4] = {s4.x, s4.y, s4.z, s4.w};
            int dv[4] = {d4.x, d4.y, d4.z, d4.w};
            #pragma unroll
            for (int k = 0; k < 4; k++) {
                uint32_t s = (uint32_t)sv[k], d = (uint32_t)dv[k];
                bS[k] = s >> 8; vS[k] = ((s & 255u) << 17) | d;
                bD[k] = d >> 8; vD[k] = (uint8_t)(d & 255u);
                hS[k] = true; hD[k] = true;
            }
        } else {
            #pragma unroll
            for (int k = 0; k < 4; k++) {
                int e = e0 + k;
                bool ok = e < end;
                hS[k] = ok; hD[k] = ok;
                if (ok) {
                    uint32_t s = (uint32_t)src[e], d = (uint32_t)dst[e];
                    bS[k] = s >> 8; vS[k] = ((s & 255u) << 17) | d;
                    bD[k] = d >> 8; vD[k] = (uint8_t)(d & 255u);
                } else { bS[k] = 0; bD[k] = 0; vS[k] = 0; vD[k] = 0; }
            }
        }
        while (true) {
            if (tid == 0) again = 0;
            __syncthreads();
            #pragma unroll
            for (int k = 0; k < 4; k++) {
                if (hS[k]) {
                    uint32_t p = atomicAdd(&pendS[bS[k]], 1u);
                    if (p < CAPS) { stS[bS[k] * CAPS + p] = vS[k]; hS[k] = false; }
                }
                if (hD[k]) {
                    uint32_t p = atomicAdd(&pendD[bD[k]], 1u);
                    if (p < CAPD) { stD[bD[k] * CAPD + p] = vD[k]; hD[k] = false; }
                }
            }
            if (hS[0] | hS[1] | hS[2] | hS[3] | hD[0] | hD[1] | hD[2] | hD[3]) again = 1;
            __syncthreads();
            for (int bb = tid; bb < nb; bb += T) {
                uint32_t n = min(pendS[bb], (uint32_t)CAPS);
                if (n == CAPS) {
                    uint32_t g = gposS[bb];            // multiple of 8 -> 32B aligned
                    uint4* dstp = (uint4*)(sortedS + g);
                    const uint4* srcp = (const uint4*)(stS + bb * CAPS);
                    dstp[0] = srcp[0]; dstp[1] = srcp[1];
                    dstp[2] = srcp[2]; dstp[3] = srcp[3];
                    gposS[bb] = g + CAPS;
                    pendS[bb] = 0u;
                } else pendS[bb] = n;
                n = min(pendD[bb], (uint32_t)CAPD);
                if (n == CAPD) {
                    uint32_t g = gposD[bb];
                    #pragma unroll
                    for (int k = 0; k < CAPD; k++) sortedD[g + k] = stD[bb * CAPD + k];
                    gposD[bb] = g + CAPD;
                    pendD[bb] = 0u;
                } else pendD[bb] = n;
            }
            __syncthreads();
            const int cont = again;     // read flag into register...
            __syncthreads();            // ...and fence before tid0 resets it
            if (!cont) break;
        }
    }
    // final flush: S padded to rup8(n) with sentinels (region exact), D exact.
    for (int bb = tid; bb < nb; bb += T) {
        uint32_t n = pendS[bb];
        if (n > 0) {
            uint32_t g = gposS[bb];
            uint32_t m = rup8(n);
            uint32_t tmp[CAPS];
            for (uint32_t k = 0; k < m; k++) tmp[k] = (k < n) ? stS[bb * CAPS + k] : sentinel;
            for (uint32_t k = 0; k < m; k += 8) {
                uint4* dstp = (uint4*)(sortedS + g + k);
                dstp[0] = *(const uint4*)(tmp + k);
                dstp[1] = *(const uint4*)(tmp + k + 4);
            }
        }
        uint32_t nD = pendD[bb], gD = gposD[bb];
        for (uint32_t k = 0; k < nD; k++) sortedD[gD + k] = stD[bb * CAPD + k];
    }
}

// In-degree + r0 fused; block owns 256 nodes; dual LDS copies; T=512.
__global__ __launch_bounds__(512) void cntb_kernel(
        const uint8_t* __restrict__ sortedD, const uint32_t* __restrict__ bstartD,
        float* __restrict__ cnt, float* __restrict__ rA, float* __restrict__ rB,
        int nn, float invN) {
    int b = blockIdx.x, tid = threadIdx.x;
    __shared__ uint32_t c[2][256];
    ((uint32_t*)c)[tid] = 0u;
    __syncthreads();
    const int cp = tid & 1;
    uint32_t beg = bstartD[b], end = bstartD[b + 1];
    for (uint32_t e = beg + tid; e < end; e += 512) atomicAdd(&c[cp][sortedD[e]], 1u);
    __syncthreads();
    if (b == 0 && tid == 0) { rA[nn] = 0.0f; rB[nn] = 0.0f; }
    int v = b * 256 + tid;
    if (tid < 256 && v < nn) {
        float cf = (float)(c[0][tid] + c[1][tid]);
        cnt[v] = cf;
        rA[v] = invN / fmaxf(cf, 1.0f);
    }
}

// a_out[v] = sum_{e: src=v} r_in[dst[e]]; fused r_out = a_out/max(cnt,1).
__global__ __launch_bounds__(512) void scatb_kernel(
        const uint32_t* __restrict__ sortedS, const uint32_t* __restrict__ bstartS,
        const float* __restrict__ rin, const float* __restrict__ cnt,
        float* __restrict__ aout, float* __restrict__ rout, int nn) {
    int b = blockIdx.x, tid = threadIdx.x;
    __shared__ float acc[2][256];
    ((float*)acc)[tid] = 0.0f;
    __syncthreads();
    const int cp = tid & 1;
    uint32_t beg = bstartS[b], end = bstartS[b + 1];   // both multiples of 8
    for (uint32_t e = beg + tid * 4; e < end; e += 512 * 4) {
        uint4 p = *(const uint4*)(sortedS + e);
        atomicAdd(&acc[cp][p.x >> 17], rin[p.x & 0x1FFFFu]);
        atomicAdd(&acc[cp][p.y >> 17], rin[p.y & 0x1FFFFu]);
        atomicAdd(&acc[cp][p.z >> 17], rin[p.z & 0x1FFFFu]);
        atomicAdd(&acc[cp][p.w >> 17], rin[p.w & 0x1FFFFu]);
    }
    __syncthreads();
    int v = b * 256 + tid;
    if (tid < 256 && v < nn) {
        float a = acc[0][tid] + acc[1][tid];
        aout[v] = a;
        if (rout) rout[v] = a / fmaxf(cnt[v], 1.0f);
    }
}

// FUSED third scatter + weighted-column-sum: block b computes a3 for its 256
// nodes in LDS (never written to global), then accumulates this block's
// contribution to {sum x, sum a1*x, sum a2*x, sum a3*x, sum a1, sum a2} and
// writes one Xpart row. a1,a2 come from the two prior scatb dispatches.
__global__ __launch_bounds__(512) void scatx_kernel(
        const uint32_t* __restrict__ sortedS, const uint32_t* __restrict__ bstartS,
        const float* __restrict__ rin, const float* __restrict__ x,
        const float* __restrict__ a1, const float* __restrict__ a2,
        float* __restrict__ Xpart, int nn) {
    const int b = blockIdx.x, tid = threadIdx.x;
    __shared__ float acc[2][256];
    ((float*)acc)[tid] = 0.0f;
    __syncthreads();
    const int cp = tid & 1;
    uint32_t beg = bstartS[b], end = bstartS[b + 1];
    for (uint32_t e = beg + tid * 4; e < end; e += 512 * 4) {
        uint4 p = *(const uint4*)(sortedS + e);
        atomicAdd(&acc[cp][p.x >> 17], rin[p.x & 0x1FFFFu]);
        atomicAdd(&acc[cp][p.y >> 17], rin[p.y & 0x1FFFFu]);
        atomicAdd(&acc[cp][p.z >> 17], rin[p.z & 0x1FFFFu]);
        atomicAdd(&acc[cp][p.w >> 17], rin[p.w & 0x1FFFFu]);
    }
    __syncthreads();
    // xpass part: thread (rs = tid>>4 in 0..31, cg = tid&15 -> 4 cols each)
    const int cg = tid & 15, rs = tid >> 4;
    float4 c0 = {0,0,0,0}, c1 = {0,0,0,0}, c2 = {0,0,0,0}, c3 = {0,0,0,0};
    float ss1 = 0.f, ss2 = 0.f;
    const int vbase = b * 256;
    for (int r = rs; r < 256; r += 32) {
        int v = vbase + r;
        if (v >= nn) break;
        float4 xv = *(const float4*)(x + (size_t)v * D + cg * 4);
        float w1 = a1[v], w2 = a2[v];
        float w3 = acc[0][r] + acc[1][r];
        c0.x += xv.x; c0.y += xv.y; c0.z += xv.z; c0.w += xv.w;
        c1.x = fmaf(w1, xv.x, c1.x); c1.y = fmaf(w1, xv.y, c1.y);
        c1.z = fmaf(w1, xv.z, c1.z); c1.w = fmaf(w1, xv.w, c1.w);
        c2.x = fmaf(w2, xv.x, c2.x); c2.y = fmaf(w2, xv.y, c2.y);
        c2.z = fmaf(w2, xv.z, c2.z); c2.w = fmaf(w2, xv.w, c2.w);
        c3.x = fmaf(w3, xv.x, c3.x); c3.y = fmaf(w3, xv.y, c3.y);
        c3.z = fmaf(w3, xv.z, c3.z); c3.w = fmaf(w3, xv.w, c3.w);
        if (cg == 0) { ss1 += w1; ss2 += w2; }
    }
    __shared__ float4 sm[4][32][16];   // [set][rs][cg]
    __shared__ float sms1[32], sms2[32];
    sm[0][rs][cg] = c0; sm[1][rs][cg] = c1; sm[2][rs][cg] = c2; sm[3][rs][cg] = c3;
    if (cg == 0) { sms1[rs] = ss1; sms2[rs] = ss2; }
    __syncthreads();
    for (int s = 16; s; s >>= 1) {
        if (rs < s) {
            #pragma unroll
            for (int k = 0; k < 4; k++) {
                float4 a = sm[k][rs][cg], bb = sm[k][rs + s][cg];
                a.x += bb.x; a.y += bb.y; a.z += bb.z; a.w += bb.w;
                sm[k][rs][cg] = a;
            }
            if (cg == 0) { sms1[rs] += sms1[rs + s]; sms2[rs] += sms2[rs + s]; }
        }
        __syncthreads();
    }
    float* outp = Xpart + (size_t)b * XPST;
    if (tid < 256) {
        int k = tid >> 6, col = tid & 63;
        outp[tid] = ((const float*)&sm[k][0][col >> 2])[col & 3];
    }
    if (tid == 0) outp[256] = sms1[0];
    if (tid == 1) outp[257] = sms2[0];
}

// Reduce Xpart over rows -> X. grid = 258 blocks, 64 threads.
__global__ __launch_bounds__(64) void xreduce_kernel(
        const float* __restrict__ Xpart, float* __restrict__ X, int nxb) {
    int j = blockIdx.x;           // 0..257
    int lane = threadIdx.x;
    float s = 0.f;
    for (int b = lane; b < nxb; b += 64) s += Xpart[(size_t)b * XPST + j];
    #pragma unroll
    for (int off = 32; off; off >>= 1) s += __shfl_down(s, off);
    if (lane == 0) X[j] = s;
}

// Chain of 64x64 matvecs; 256 threads.
__global__ __launch_bounds__(256) void final_kernel(const float* __restrict__ X,
    const float* __restrict__ Wl1, const float* __restrict__ bl1, const float* __restrict__ Wr1,
    const float* __restrict__ Wl2, const float* __restrict__ bl2, const float* __restrict__ Wr2,
    const float* __restrict__ Wl3, const float* __restrict__ bl3, const float* __restrict__ Wr3,
    const float* __restrict__ Wlin, const float* __restrict__ blin,
    float* __restrict__ out, int nn) {
    const int tid = threadIdx.x;
    const int t = tid >> 2, q = tid & 3, c0 = q * 16;
    __shared__ float X1[D], X2[D], X3[D], X4[D];
    __shared__ float m1u[D], m1a1[D], m1a2[D], m2u[D], m2a1[D];
    __shared__ float sred[4];
    if (tid < 64)       X1[tid]       = X[tid] * (1.0f / (float)nn);
    else if (tid < 128) X2[tid - 64]  = X[tid];
    else if (tid < 192) X3[tid - 128] = X[tid];
    else                X4[tid - 192] = X[tid];
    const float s1 = X[4 * D], s2 = X[4 * D + 1];
    __syncthreads();

    float dl2 = 0.f, dl3 = 0.f, dl4 = 0.f, dr1 = 0.f, dr2 = 0.f, dr3 = 0.f;
    #pragma unroll
    for (int k = 0; k < 16; k++) {
        int c = c0 + k;
        float wl = Wl1[t * D + c], wr = Wr1[t * D + c];
        dl2 = fmaf(wl, X2[c], dl2); dl3 = fmaf(wl, X3[c], dl3); dl4 = fmaf(wl, X4[c], dl4);
        dr1 = fmaf(wr, X1[c], dr1); dr2 = fmaf(wr, X2[c], dr2); dr3 = fmaf(wr, X3[c], dr3);
    }
    #define RED4(v) { v += __shfl_down(v, 2, 4); v += __shfl_down(v, 1, 4); }
    RED4(dl2) RED4(dl3) RED4(dl4) RED4(dr1) RED4(dr2) RED4(dr3)
    if (q == 0) {
        m1u[t]  = dl2 + bl1[t]      + dr1;
        m1a1[t] = dl3 + bl1[t] * s1 + dr2;
        m1a2[t] = dl4 + bl1[t] * s2 + dr3;
    }
    __syncthreads();

    float el1 = 0.f, el2 = 0.f, er0 = 0.f, er1 = 0.f;
    #pragma unroll
    for (int k = 0; k < 16; k++) {
        int c = c0 + k;
        float wl = Wl2[t * D + c], wr = Wr2[t * D + c];
        el1 = fmaf(wl, m1a1[c], el1); el2 = fmaf(wl, m1a2[c], el2);
        er0 = fmaf(wr, m1u[c],  er0); er1 = fmaf(wr, m1a1[c], er1);
    }
    RED4(el1) RED4(el2) RED4(er0) RED4(er1)
    if (q == 0) {
        m2u[t]  = el1 + bl2[t]      + er0;
        m2a1[t] = el2 + bl2[t] * s1 + er1;
    }
    __syncthreads();

    float fl = 0.f, fr = 0.f;
    #pragma unroll
    for (int k = 0; k < 16; k++) {
        int c = c0 + k;
        fl = fmaf(Wl3[t * D + c], m2a1[c], fl);
        fr = fmaf(Wr3[t * D + c], m2u[c],  fr);
    }
    RED4(fl) RED4(fr)
    float contrib = 0.f;
    if (q == 0) contrib = Wlin[t] * (fl + bl3[t] + fr);
    #pragma unroll
    for (int off = 32; off; off >>= 1) contrib += __shfl_down(contrib, off);
    if ((tid & 63) == 0) sred[tid >> 6] = contrib;
    __syncthreads();
    if (tid == 0) out[0] = sred[0] + sred[1] + sred[2] + sred[3] + blin[0];
}

extern "C" void kernel_launch(void* const* d_in, const int* in_sizes, int n_in,
                              void* d_out, int out_size, void* d_ws, size_t ws_size,
                              hipStream_t stream) {
    const float* x    = (const float*)d_in[0];
    const int*   ei   = (const int*)d_in[1];
    const float* Wl1  = (const float*)d_in[2];
    const float* bl1  = (const float*)d_in[3];
    const float* Wr1  = (const float*)d_in[4];
    const float* Wl2  = (const float*)d_in[5];
    const float* bl2  = (const float*)d_in[6];
    const float* Wr2  = (const float*)d_in[7];
    const float* Wl3  = (const float*)d_in[8];
    const float* bl3  = (const float*)d_in[9];
    const float* Wr3  = (const float*)d_in[10];
    const float* Wlin = (const float*)d_in[11];
    const float* blin = (const float*)d_in[12];
    float* out = (float*)d_out;

    const int nn = in_sizes[0] / D;        // 100000
    const int ne = in_sizes[1] / 2;        // 3200000
    const int* srcIdx = ei;
    const int* dstIdx = ei + ne;
    const int nb = (nn + 255) >> 8;        // 391

    char* base = (char*)d_ws;
    size_t cur = 0;
    auto alloc = [&](size_t bytes) -> void* {
        void* p = base + cur;
        cur = (cur + bytes + 255) & ~(size_t)255;
        return p;
    };
    float*    cnt      = (float*)alloc((size_t)nn * 4);
    float*    a1       = (float*)alloc((size_t)nn * 4);
    float*    a2       = (float*)alloc((size_t)nn * 4);
    float*    a3       = (float*)alloc((size_t)nn * 4);           // fallback only
    float*    rA       = (float*)alloc((size_t)(nn + 1) * 4);     // +1 sentinel
    float*    rB       = (float*)alloc((size_t)(nn + 1) * 4);
    float*    X        = (float*)alloc((4 * D + 2) * 4);
    float*    Xpart    = (float*)alloc((size_t)XPB * XPST * 4);
    size_t    zend     = cur;
    uint32_t* blkhistS = (uint32_t*)alloc((size_t)PNBLK * nb * 4);
    uint32_t* blkhistD = (uint32_t*)alloc((size_t)PNBLK * nb * 4);
    uint32_t* offsS    = (uint32_t*)alloc((size_t)PNBLK * nb * 4);
    uint32_t* offsD    = (uint32_t*)alloc((size_t)PNBLK * nb * 4);
    uint32_t* bstartS  = (uint32_t*)alloc((size_t)(nb + 1) * 4);
    uint32_t* bstartD  = (uint32_t*)alloc((size_t)(nb + 1) * 4);
    uint32_t* totS     = (uint32_t*)alloc((size_t)nb * 4);
    uint32_t* totD     = (uint32_t*)alloc((size_t)nb * 4);
    uint32_t* sortedS  = (uint32_t*)alloc(((size_t)ne + (size_t)PNBLK * nb * 7) * 4); // padded
    uint8_t*  sortedD  = (uint8_t*)alloc((size_t)ne);
    const size_t need = cur;

    const int B = 256;
    if (need <= ws_size && nn <= 131071 && nb <= NBMAX) {
        const int chunk = ((ne + PNBLK - 1) / PNBLK + 3) & ~3;
        hipLaunchKernelGGL(hist_kernel, dim3(PNBLK), dim3(512), 0, stream,
                           srcIdx, dstIdx, blkhistS, blkhistD, ne, nb, chunk);
        hipLaunchKernelGGL(reduceoffs_kernel, dim3(2 * nb), dim3(64), 0, stream,
                           blkhistS, blkhistD, offsS, offsD, totS, totD, nb);
        hipLaunchKernelGGL(scan_kernel, dim3(2), dim3(512), 0, stream,
                           totS, totD, bstartS, bstartD, nb);
        hipLaunchKernelGGL(place_kernel, dim3(PNBLK), dim3(512), 0, stream,
                           srcIdx, dstIdx, offsS, offsD, bstartS, bstartD,
                           sortedS, sortedD, ne, nb, chunk, (uint32_t)nn);
        hipLaunchKernelGGL(cntb_kernel, dim3(nb), dim3(512), 0, stream,
                           sortedD, bstartD, cnt, rA, rB, nn, 1.0f / (float)nn);
        hipLaunchKernelGGL(scatb_kernel, dim3(nb), dim3(512), 0, stream,
                           sortedS, bstartS, rA, cnt, a1, rB, nn);
        hipLaunchKernelGGL(scatb_kernel, dim3(nb), dim3(512), 0, stream,
                           sortedS, bstartS, rB, cnt, a2, rA, nn);
        hipLaunchKernelGGL(scatx_kernel, dim3(nb), dim3(512), 0, stream,
                           sortedS, bstartS, rA, x, a1, a2, Xpart, nn);
        hipLaunchKernelGGL(xreduce_kernel, dim3(4 * D + 2), dim3(64), 0, stream,
                           Xpart, X, nb);
    } else {
        const int zn = (int)(zend / 4);
        hipLaunchKernelGGL(zero_kernel, dim3((zn + B - 1) / B), dim3(B), 0, stream, (float*)d_ws, zn);
        hipLaunchKernelGGL(cnt_kernel,  dim3((ne + B - 1) / B), dim3(B), 0, stream, dstIdx, cnt, ne);
        hipLaunchKernelGGL(r0_kernel,   dim3((nn + B - 1) / B), dim3(B), 0, stream, cnt, rA, nn);
        hipLaunchKernelGGL(scatter_kernel, dim3((ne + B - 1) / B), dim3(B), 0, stream, srcIdx, dstIdx, rA, a1, ne);
        hipLaunchKernelGGL(rdiv_kernel, dim3((nn + B - 1) / B), dim3(B), 0, stream, a1, cnt, rA, nn);
        hipLaunchKernelGGL(scatter_kernel, dim3((ne + B - 1) / B), dim3(B), 0, stream, srcIdx, dstIdx, rA, a2, ne);
        hipLaunchKernelGGL(rdiv_kernel, dim3((nn + B - 1) / B), dim3(B), 0, stream, a2, cnt, rA, nn);
        hipLaunchKernelGGL(scatter_kernel, dim3((ne + B - 1) / B), dim3(B), 0, stream, srcIdx, dstIdx, rA, a3, ne);
        hipLaunchKernelGGL(xpass_kernel, dim3(XPB), dim3(B), 0, stream, x, a1, a2, a3, Xpart, nn);
        hipLaunchKernelGGL(xreduce_kernel, dim3(4 * D + 2), dim3(64), 0, stream, Xpart, X, XPB);
    }

    hipLaunchKernelGGL(final_kernel, dim3(1), dim3(B), 0, stream, X,
                       Wl1, bl1, Wr1, Wl2, bl2, Wr2, Wl3, bl3, Wr3, Wlin, blin, out, nn);
}